// Round 2
// baseline (885.404 us; speedup 1.0000x reference)
//
#include <hip/hip_runtime.h>
#include <hip/hip_bf16.h>
#include <math.h>

#define B_ 8
#define N_ 4096
#define C_ 256
#define H_ 8
#define HD_ 32
#define BN_ (B_ * N_)  // 32768

// powers[c] = 1 + 4*sigmoid(power_p[c]),  c = h*32+d  (256 values)
__global__ void pow_init(const float* __restrict__ pp, float* __restrict__ powers) {
    int t = threadIdx.x;
    float v = pp[t];
    powers[t] = 1.0f + 4.0f / (1.0f + expf(-v));
}

// Fused GEMM: Y = x @ [W_qg | W_kv]  (32768x256)@(256x1024)
// Epilogue: col<256 -> q_pow=|y|^p ; <512 -> g ; <768 -> k_pow=|y|^p ; else v_nc
__global__ __launch_bounds__(256) void gemm_qgkv(
    const float* __restrict__ x,
    const float* __restrict__ Wqg,
    const float* __restrict__ Wkv,
    const float* __restrict__ powers,
    float* __restrict__ q_pow, float* __restrict__ g_buf,
    float* __restrict__ k_pow, float* __restrict__ v_nc)
{
    __shared__ float As[16][64];
    __shared__ float Bs[16][64];
    int t = threadIdx.x;
    int row0 = blockIdx.x * 64;
    int col0 = blockIdx.y * 64;  // 0..1023 in steps of 64
    int tx = t & 15, ty = t >> 4;
    float acc[4][4] = {};
    for (int k0 = 0; k0 < 256; k0 += 16) {
        for (int i = 0; i < 4; i++) {
            int idx = t + i * 256;
            int r = idx >> 4, cc = idx & 15;
            As[cc][r] = x[(size_t)(row0 + r) * 256 + k0 + cc];
        }
        for (int i = 0; i < 4; i++) {
            int idx = t + i * 256;
            int r = idx >> 6, c = idx & 63;
            int col = col0 + c;
            float w;
            if (col < 512) w = Wqg[(size_t)(k0 + r) * 512 + col];
            else           w = Wkv[(size_t)(k0 + r) * 512 + (col - 512)];
            Bs[r][c] = w;
        }
        __syncthreads();
        for (int k = 0; k < 16; k++) {
            float a[4], b[4];
            #pragma unroll
            for (int i = 0; i < 4; i++) a[i] = As[k][ty * 4 + i];
            #pragma unroll
            for (int j = 0; j < 4; j++) b[j] = Bs[k][tx * 4 + j];
            #pragma unroll
            for (int i = 0; i < 4; i++)
                #pragma unroll
                for (int j = 0; j < 4; j++) acc[i][j] += a[i] * b[j];
        }
        __syncthreads();
    }
    for (int i = 0; i < 4; i++) {
        int R = row0 + ty * 4 + i;
        for (int j = 0; j < 4; j++) {
            int col = col0 + tx * 4 + j;
            float v = acc[i][j];
            if (col < 256) {
                float av = fabsf(v);
                q_pow[(size_t)R * 256 + col] = (av > 0.f) ? powf(av, powers[col]) : 0.f;
            } else if (col < 512) {
                g_buf[(size_t)R * 256 + (col - 256)] = v;
            } else if (col < 768) {
                int c = col - 512;
                float av = fabsf(v);
                k_pow[(size_t)R * 256 + c] = (av > 0.f) ? powf(av, powers[c]) : 0.f;
            } else {
                v_nc[(size_t)R * 256 + (col - 768)] = v;
            }
        }
    }
}

// kv_mat[bh][d][e] = sum_n k_pow[b,n,h*32+d] * v_nc[b,n,h*32+e]   (64 blocks)
__global__ __launch_bounds__(256) void kvmat_kernel(
    const float* __restrict__ k_pow, const float* __restrict__ v_nc,
    float* __restrict__ kv_mat)
{
    __shared__ float Kl[16][32];
    __shared__ float Vl[16][32];
    int t = threadIdx.x;
    int bh = blockIdx.x;
    int b = bh >> 3, h = bh & 7;
    int d = t & 31, e0 = (t >> 5) * 4;
    float acc[4] = {0.f, 0.f, 0.f, 0.f};
    const size_t base = (size_t)b * N_ * 256 + h * 32;
    for (int n0 = 0; n0 < N_; n0 += 16) {
        for (int i = 0; i < 4; i++) {
            int idx = t + i * 256;  // 0..1023
            int nn = (idx >> 5) & 15, dd = idx & 31;
            if (idx < 512) Kl[nn][dd] = k_pow[base + (size_t)(n0 + nn) * 256 + dd];
            else           Vl[nn][dd] = v_nc[base + (size_t)(n0 + nn) * 256 + dd];
        }
        __syncthreads();
        #pragma unroll
        for (int nn = 0; nn < 16; nn++) {
            float kd = Kl[nn][d];
            #pragma unroll
            for (int j = 0; j < 4; j++) acc[j] += kd * Vl[nn][e0 + j];
        }
        __syncthreads();
    }
    #pragma unroll
    for (int j = 0; j < 4; j++) kv_mat[(size_t)bh * 1024 + d * 32 + e0 + j] = acc[j];
}

// att[R,c=h*32+e] = sum_d q_pow[R,h*32+d] * kv_mat[b*8+h][d][e]  (in-place over q_pow)
__global__ __launch_bounds__(256) void att_kernel(
    float* __restrict__ q_att, const float* __restrict__ kv_mat)
{
    __shared__ float kvm[8192];
    __shared__ float ql[256];
    int t = threadIdx.x;
    int R0 = blockIdx.x * 16;
    int b = R0 >> 12;
    for (int i = 0; i < 32; i++) kvm[t + i * 256] = kv_mat[(size_t)b * 8192 + t + i * 256];
    int h = t >> 5, e = t & 31;
    const float* kvh = &kvm[h * 1024];
    for (int r = 0; r < 16; r++) {
        __syncthreads();
        ql[t] = q_att[(size_t)(R0 + r) * 256 + t];
        __syncthreads();
        float acc = 0.f;
        #pragma unroll
        for (int d = 0; d < 32; d++) acc += ql[h * 32 + d] * kvh[d * 32 + e];
        q_att[(size_t)(R0 + r) * 256 + t] = acc;
    }
}

// Depthwise 5x5 conv. Image (G,DD) = contiguous slice v_nc[(G*32+DD)*4096 .. +4096] as 64x64.
__global__ __launch_bounds__(256) void conv_kernel(
    const float* __restrict__ v_nc,
    const float* __restrict__ w, const float* __restrict__ bias,
    float* __restrict__ vloc)
{
    __shared__ float img[4096];
    __shared__ float wl[25];
    int t = threadIdx.x;
    int gid = blockIdx.x;     // G*32 + DD
    int DD = gid & 31;
    for (int i = 0; i < 16; i++) img[t + i * 256] = v_nc[(size_t)gid * 4096 + t + i * 256];
    if (t < 25) wl[t] = w[DD * 25 + t];
    __syncthreads();
    float bs = bias[DD];
    for (int i = 0; i < 16; i++) {
        int p = t + i * 256;
        int y = p >> 6, xx = p & 63;
        float acc = 0.f;
        #pragma unroll
        for (int ky = 0; ky < 5; ky++) {
            int yy = y + ky - 2;
            if (yy < 0 || yy >= 64) continue;
            #pragma unroll
            for (int kx = 0; kx < 5; kx++) {
                int xc = xx + kx - 2;
                if (xc < 0 || xc >= 64) continue;
                acc += wl[ky * 5 + kx] * img[yy * 64 + xc];
            }
        }
        vloc[(size_t)gid * 4096 + p] = acc + bs;
    }
}

// out = ((att + vloc_shuffled) * g) @ W_proj + b_proj, f32 out.
// A[R, c] = (att[R,c] + vloc[((b*8+(c&7))*32+(c>>3))*4096 + n]) * g[R,c]
__global__ __launch_bounds__(256) void gemm_out(
    const float* __restrict__ att, const float* __restrict__ vloc,
    const float* __restrict__ g_buf,
    const float* __restrict__ Wp, const float* __restrict__ bp,
    float* __restrict__ out)
{
    __shared__ float As[16][64];
    __shared__ float Bs[16][64];
    int t = threadIdx.x;
    int row0 = blockIdx.x * 64;
    int col0 = blockIdx.y * 64;
    int tx = t & 15, ty = t >> 4;
    float acc[4][4] = {};
    for (int k0 = 0; k0 < 256; k0 += 16) {
        for (int i = 0; i < 4; i++) {
            int idx = t + i * 256;
            int r = idx >> 4, cc = idx & 15;
            int R = row0 + r;
            int c = k0 + cc;
            int b = R >> 12, n = R & 4095;
            float a = att[(size_t)R * 256 + c];
            float vl = vloc[(size_t)((b * 8 + (c & 7)) * 32 + (c >> 3)) * 4096 + n];
            float gg = g_buf[(size_t)R * 256 + c];
            As[cc][r] = (a + vl) * gg;
        }
        for (int i = 0; i < 4; i++) {
            int idx = t + i * 256;
            int r = idx >> 6, c = idx & 63;
            Bs[r][c] = Wp[(size_t)(k0 + r) * 256 + col0 + c];
        }
        __syncthreads();
        for (int k = 0; k < 16; k++) {
            float a[4], b[4];
            #pragma unroll
            for (int i = 0; i < 4; i++) a[i] = As[k][ty * 4 + i];
            #pragma unroll
            for (int j = 0; j < 4; j++) b[j] = Bs[k][tx * 4 + j];
            #pragma unroll
            for (int i = 0; i < 4; i++)
                #pragma unroll
                for (int j = 0; j < 4; j++) acc[i][j] += a[i] * b[j];
        }
        __syncthreads();
    }
    for (int i = 0; i < 4; i++) {
        int R = row0 + ty * 4 + i;
        for (int j = 0; j < 4; j++) {
            int col = col0 + tx * 4 + j;
            out[(size_t)R * 256 + col] = acc[i][j] + bp[col];
        }
    }
}

extern "C" void kernel_launch(void* const* d_in, const int* in_sizes, int n_in,
                              void* d_out, int out_size, void* d_ws, size_t ws_size,
                              hipStream_t stream) {
    const float* x      = (const float*)d_in[0];
    const float* W_qg   = (const float*)d_in[1];
    const float* W_kv   = (const float*)d_in[2];
    const float* W_proj = (const float*)d_in[3];
    const float* b_proj = (const float*)d_in[4];
    const float* dwc_w  = (const float*)d_in[5];
    const float* dwc_b  = (const float*)d_in[6];
    const float* pow_p  = (const float*)d_in[7];
    float* out = (float*)d_out;

    float* ws = (float*)d_ws;
    const size_t E = (size_t)BN_ * C_;  // 8388608
    float* q_att  = ws;           // q_pow, then att in-place
    float* g_buf  = ws + E;
    float* k_vloc = ws + 2 * E;   // k_pow, then vloc (after kvmat)
    float* v_nc   = ws + 3 * E;
    float* kv_mat = ws + 4 * E;          // 65536 floats
    float* powers = ws + 4 * E + 65536;  // 256 floats

    pow_init<<<1, 256, 0, stream>>>(pow_p, powers);
    gemm_qgkv<<<dim3(BN_ / 64, 1024 / 64), 256, 0, stream>>>(
        x, W_qg, W_kv, powers, q_att, g_buf, k_vloc, v_nc);
    kvmat_kernel<<<64, 256, 0, stream>>>(k_vloc, v_nc, kv_mat);
    att_kernel<<<BN_ / 16, 256, 0, stream>>>(q_att, kv_mat);
    conv_kernel<<<2048, 256, 0, stream>>>(v_nc, dwc_w, dwc_b, k_vloc);
    gemm_out<<<dim3(BN_ / 64, C_ / 64), 256, 0, stream>>>(
        q_att, k_vloc, g_buf, W_proj, b_proj, out);
}

// Round 3
// 381.234 us; speedup vs baseline: 2.3225x; 2.3225x over previous
//
#include <hip/hip_runtime.h>
#include <hip/hip_bf16.h>
#include <math.h>

#define B_ 8
#define N_ 4096
#define C_ 256
#define H_ 8
#define HD_ 32
#define BN_ (B_ * N_)  // 32768
#define E_ ((size_t)BN_ * C_)  // 8388608

typedef __attribute__((ext_vector_type(8))) short short8;
typedef __attribute__((ext_vector_type(4))) float f32x4;

__device__ __forceinline__ float b2f(__hip_bfloat16 x) { return __bfloat162float(x); }

// async global->LDS, 16 bytes per lane; lds base must be wave-uniform
__device__ __forceinline__ void gl_lds16(const void* gp, void* lp) {
    __builtin_amdgcn_global_load_lds(
        (const __attribute__((address_space(1))) unsigned int*)gp,
        (__attribute__((address_space(3))) unsigned int*)lp,
        16, 0, 0);
}

// ---- convert x (fp32 -> bf16), vectorized ----
__global__ __launch_bounds__(256) void cvt_x(const float* __restrict__ x,
                                             __hip_bfloat16* __restrict__ xb) {
    size_t i = ((size_t)blockIdx.x * 256 + threadIdx.x) * 4;
    float4 v = *(const float4*)&x[i];
    xb[i + 0] = __float2bfloat16(v.x);
    xb[i + 1] = __float2bfloat16(v.y);
    xb[i + 2] = __float2bfloat16(v.z);
    xb[i + 3] = __float2bfloat16(v.w);
}

// ---- convert + transpose weights to [N][K] bf16; also powers ----
__global__ __launch_bounds__(256) void cvt_w(
    const float* __restrict__ Wqg, const float* __restrict__ Wkv,
    const float* __restrict__ Wp, const float* __restrict__ pp,
    __hip_bfloat16* __restrict__ Wt1, __hip_bfloat16* __restrict__ Wt2,
    float* __restrict__ powers) {
    int bid = blockIdx.x, t = threadIdx.x;
    if (bid < 1024) {
        int n = bid;
        float v = (n < 512) ? Wqg[(size_t)t * 512 + n] : Wkv[(size_t)t * 512 + (n - 512)];
        Wt1[(size_t)n * 256 + t] = __float2bfloat16(v);
    } else if (bid < 1280) {
        int n = bid - 1024;
        Wt2[(size_t)n * 256 + t] = __float2bfloat16(Wp[(size_t)t * 256 + n]);
    } else {
        powers[t] = 1.0f + 4.0f / (1.0f + expf(-pp[t]));
    }
}

// ---- GEMM1: (32768x256 bf16) @ (256x1024 via Wt1[n][k]) -> epilogue split ----
// grid (256, 8); block tile 128x128, BK=32
__global__ __launch_bounds__(256) void gemm1_mfma(
    const __hip_bfloat16* __restrict__ xb, const __hip_bfloat16* __restrict__ Wt1,
    const float* __restrict__ powers,
    float* __restrict__ q_pow, float* __restrict__ k_pow,
    __hip_bfloat16* __restrict__ g16, __hip_bfloat16* __restrict__ v16)
{
    __shared__ __align__(16) short As[128 * 32];
    __shared__ __align__(16) short Bs[128 * 32];
    int t = threadIdx.x;
    int w = t >> 6, l = t & 63;
    int row0 = blockIdx.x * 128;
    int col0 = blockIdx.y * 128;
    int wm = (w >> 1) * 64, wn = (w & 1) * 64;
    int lane15 = l & 15, quad = l >> 4;
    int rr = (l >> 2), kk = (l & 3) * 8;

    f32x4 acc[4][4];
    #pragma unroll
    for (int mi = 0; mi < 4; mi++)
        #pragma unroll
        for (int ni = 0; ni < 4; ni++) acc[mi][ni] = (f32x4){0.f, 0.f, 0.f, 0.f};

    for (int k0 = 0; k0 < 256; k0 += 32) {
        #pragma unroll
        for (int i = 0; i < 2; i++) {
            int r = (w * 2 + i) * 16 + rr;
            gl_lds16(&xb[(size_t)(row0 + r) * 256 + k0 + kk], &As[(w * 2 + i) * 512]);
            gl_lds16(&Wt1[(size_t)(col0 + r) * 256 + k0 + kk], &Bs[(w * 2 + i) * 512]);
        }
        __syncthreads();
        short8 a[4], b[4];
        #pragma unroll
        for (int mi = 0; mi < 4; mi++)
            a[mi] = *(const short8*)&As[(wm + mi * 16 + lane15) * 32 + quad * 8];
        #pragma unroll
        for (int ni = 0; ni < 4; ni++)
            b[ni] = *(const short8*)&Bs[(wn + ni * 16 + lane15) * 32 + quad * 8];
        #pragma unroll
        for (int mi = 0; mi < 4; mi++)
            #pragma unroll
            for (int ni = 0; ni < 4; ni++)
                acc[mi][ni] = __builtin_amdgcn_mfma_f32_16x16x32_bf16(a[mi], b[ni], acc[mi][ni], 0, 0, 0);
        __syncthreads();
    }

    int region = blockIdx.y >> 1;  // 0:q 1:g 2:k 3:v
    #pragma unroll
    for (int mi = 0; mi < 4; mi++) {
        #pragma unroll
        for (int ni = 0; ni < 4; ni++) {
            int row = row0 + wm + mi * 16 + quad * 4;
            int col = col0 + wn + ni * 16 + lane15;
            int c255 = col & 255;
            float p = powers[c255];
            #pragma unroll
            for (int r = 0; r < 4; r++) {
                float v = acc[mi][ni][r];
                size_t idx = (size_t)(row + r) * 256 + c255;
                if (region == 0) {
                    float av = fabsf(v);
                    q_pow[idx] = (av > 0.f) ? powf(av, p) : 0.f;
                } else if (region == 1) {
                    g16[idx] = __float2bfloat16(v);
                } else if (region == 2) {
                    float av = fabsf(v);
                    k_pow[idx] = (av > 0.f) ? powf(av, p) : 0.f;
                } else {
                    v16[idx] = __float2bfloat16(v);
                }
            }
        }
    }
}

// ---- kvmat partials: grid 512 = bh*8+seg, each covers 512 n ----
__global__ __launch_bounds__(256) void kvmat_kernel(
    const float* __restrict__ k_pow, const __hip_bfloat16* __restrict__ v16,
    float* __restrict__ kv_part)
{
    __shared__ float Kl[16][32];
    __shared__ float Vl[16][32];
    int t = threadIdx.x;
    int bid = blockIdx.x;
    int bh = bid >> 3, seg = bid & 7;
    int b = bh >> 3, h = bh & 7;
    int d = t & 31, e0 = (t >> 5) * 4;
    float acc[4] = {0.f, 0.f, 0.f, 0.f};
    const size_t base = (size_t)b * N_ * 256 + h * 32;
    for (int n0 = seg * 512; n0 < (seg + 1) * 512; n0 += 16) {
        #pragma unroll
        for (int i = 0; i < 4; i++) {
            int idx = t + i * 256;
            int nn = (idx >> 5) & 15, dd = idx & 31;
            if (idx < 512) Kl[nn][dd] = k_pow[base + (size_t)(n0 + nn) * 256 + dd];
            else           Vl[nn][dd] = b2f(v16[base + (size_t)(n0 + nn) * 256 + dd]);
        }
        __syncthreads();
        #pragma unroll
        for (int nn = 0; nn < 16; nn++) {
            float kd = Kl[nn][d];
            #pragma unroll
            for (int j = 0; j < 4; j++) acc[j] += kd * Vl[nn][e0 + j];
        }
        __syncthreads();
    }
    #pragma unroll
    for (int j = 0; j < 4; j++) kv_part[(size_t)bid * 1024 + d * 32 + e0 + j] = acc[j];
}

__global__ __launch_bounds__(256) void kv_reduce(
    const float* __restrict__ kv_part, float* __restrict__ kv_mat)
{
    int bh = blockIdx.x, t = threadIdx.x;
    #pragma unroll
    for (int j = 0; j < 4; j++) {
        int i = t + j * 256;
        float s = 0.f;
        #pragma unroll
        for (int seg = 0; seg < 8; seg++) s += kv_part[((size_t)bh * 8 + seg) * 1024 + i];
        kv_mat[(size_t)bh * 1024 + i] = s;
    }
}

// ---- depthwise 5x5 conv on bf16 images ----
__global__ __launch_bounds__(256) void conv_kernel(
    const __hip_bfloat16* __restrict__ v16,
    const float* __restrict__ w, const float* __restrict__ bias,
    __hip_bfloat16* __restrict__ vloc)
{
    __shared__ float img[4096];
    __shared__ float wl[25];
    int t = threadIdx.x;
    int gid = blockIdx.x;  // G*32 + DD
    int DD = gid & 31;
    for (int i = 0; i < 16; i++) img[t + i * 256] = b2f(v16[(size_t)gid * 4096 + t + i * 256]);
    if (t < 25) wl[t] = w[DD * 25 + t];
    __syncthreads();
    float bs = bias[DD];
    for (int i = 0; i < 16; i++) {
        int p = t + i * 256;
        int y = p >> 6, xx = p & 63;
        float acc = 0.f;
        #pragma unroll
        for (int ky = 0; ky < 5; ky++) {
            int yy = y + ky - 2;
            if (yy < 0 || yy >= 64) continue;
            #pragma unroll
            for (int kx = 0; kx < 5; kx++) {
                int xc = xx + kx - 2;
                if (xc < 0 || xc >= 64) continue;
                acc += wl[ky * 5 + kx] * img[yy * 64 + xc];
            }
        }
        vloc[(size_t)gid * 4096 + p] = __float2bfloat16(acc + bs);
    }
}

// ---- att + vloc-shuffle + gate -> A2 bf16 (gemm2 A operand) ----
__global__ __launch_bounds__(256) void att_a2(
    const float* __restrict__ q_pow, const float* __restrict__ kv_mat,
    const __hip_bfloat16* __restrict__ vloc, const __hip_bfloat16* __restrict__ g16,
    __hip_bfloat16* __restrict__ A2)
{
    __shared__ float kvm[8192];
    __shared__ float ql[256];
    int t = threadIdx.x;
    int R0 = blockIdx.x * 16;
    int b = R0 >> 12, n0 = R0 & 4095;
    for (int i = 0; i < 32; i++) kvm[t + i * 256] = kv_mat[(size_t)b * 8192 + t + i * 256];
    int h = t >> 5, e = t & 31;
    int c = t;
    size_t img = (size_t)((b * 8 + (c & 7)) * 32 + (c >> 3)) * 4096 + n0;
    const float* kvh = &kvm[h * 1024];
    for (int r = 0; r < 16; r++) {
        __syncthreads();
        ql[t] = q_pow[(size_t)(R0 + r) * 256 + t];
        __syncthreads();
        float acc = 0.f;
        #pragma unroll
        for (int d = 0; d < 32; d++) acc += ql[h * 32 + d] * kvh[d * 32 + e];
        float vl = b2f(vloc[img + r]);
        float gg = b2f(g16[(size_t)(R0 + r) * 256 + c]);
        A2[(size_t)(R0 + r) * 256 + c] = __float2bfloat16((acc + vl) * gg);
    }
}

// ---- GEMM2: (32768x256 bf16 A2) @ (Wt2[n][k]) + b_proj -> fp32 out ----
__global__ __launch_bounds__(256) void gemm2_mfma(
    const __hip_bfloat16* __restrict__ A2, const __hip_bfloat16* __restrict__ Wt2,
    const float* __restrict__ bp, float* __restrict__ out)
{
    __shared__ __align__(16) short As[128 * 32];
    __shared__ __align__(16) short Bs[128 * 32];
    int t = threadIdx.x;
    int w = t >> 6, l = t & 63;
    int row0 = blockIdx.x * 128;
    int col0 = blockIdx.y * 128;
    int wm = (w >> 1) * 64, wn = (w & 1) * 64;
    int lane15 = l & 15, quad = l >> 4;
    int rr = (l >> 2), kk = (l & 3) * 8;

    f32x4 acc[4][4];
    #pragma unroll
    for (int mi = 0; mi < 4; mi++)
        #pragma unroll
        for (int ni = 0; ni < 4; ni++) acc[mi][ni] = (f32x4){0.f, 0.f, 0.f, 0.f};

    for (int k0 = 0; k0 < 256; k0 += 32) {
        #pragma unroll
        for (int i = 0; i < 2; i++) {
            int r = (w * 2 + i) * 16 + rr;
            gl_lds16(&A2[(size_t)(row0 + r) * 256 + k0 + kk], &As[(w * 2 + i) * 512]);
            gl_lds16(&Wt2[(size_t)(col0 + r) * 256 + k0 + kk], &Bs[(w * 2 + i) * 512]);
        }
        __syncthreads();
        short8 a[4], b[4];
        #pragma unroll
        for (int mi = 0; mi < 4; mi++)
            a[mi] = *(const short8*)&As[(wm + mi * 16 + lane15) * 32 + quad * 8];
        #pragma unroll
        for (int ni = 0; ni < 4; ni++)
            b[ni] = *(const short8*)&Bs[(wn + ni * 16 + lane15) * 32 + quad * 8];
        #pragma unroll
        for (int mi = 0; mi < 4; mi++)
            #pragma unroll
            for (int ni = 0; ni < 4; ni++)
                acc[mi][ni] = __builtin_amdgcn_mfma_f32_16x16x32_bf16(a[mi], b[ni], acc[mi][ni], 0, 0, 0);
        __syncthreads();
    }

    #pragma unroll
    for (int mi = 0; mi < 4; mi++) {
        #pragma unroll
        for (int ni = 0; ni < 4; ni++) {
            int row = row0 + wm + mi * 16 + quad * 4;
            int col = col0 + wn + ni * 16 + lane15;
            float bv = bp[col];
            #pragma unroll
            for (int r = 0; r < 4; r++)
                out[(size_t)(row + r) * 256 + col] = acc[mi][ni][r] + bv;
        }
    }
}

extern "C" void kernel_launch(void* const* d_in, const int* in_sizes, int n_in,
                              void* d_out, int out_size, void* d_ws, size_t ws_size,
                              hipStream_t stream) {
    const float* x      = (const float*)d_in[0];
    const float* W_qg   = (const float*)d_in[1];
    const float* W_kv   = (const float*)d_in[2];
    const float* W_proj = (const float*)d_in[3];
    const float* b_proj = (const float*)d_in[4];
    const float* dwc_w  = (const float*)d_in[5];
    const float* dwc_b  = (const float*)d_in[6];
    const float* pow_p  = (const float*)d_in[7];
    float* out = (float*)d_out;

    float* ws = (float*)d_ws;
    const size_t E = E_;
    // layout (float units):
    float* q_pow = ws;                                   // [0, E)
    float* k_pow = ws + E;                               // [E, 2E)
    __hip_bfloat16* vl16 = (__hip_bfloat16*)(ws + E);    // aliases k_pow (dead after kvmat)
    __hip_bfloat16* g16  = (__hip_bfloat16*)(ws + 2 * E);        // [2E, 2.5E)
    __hip_bfloat16* v16  = (__hip_bfloat16*)(ws + 2 * E + E / 2);// [2.5E, 3E)
    __hip_bfloat16* xb   = (__hip_bfloat16*)(ws + 3 * E);        // [3E, 3.5E), reused as A2
    __hip_bfloat16* A2   = xb;
    float* kv_part = ws + 3 * E + E / 2;                 // 512K floats
    float* kv_mat  = kv_part + 512 * 1024;               // 64K floats
    __hip_bfloat16* Wt1 = (__hip_bfloat16*)(kv_mat + 65536);     // 256K bf16
    __hip_bfloat16* Wt2 = Wt1 + 256 * 1024;              // 64K bf16
    float* powers = (float*)(Wt2 + 65536);               // 256 floats

    cvt_x<<<E / 1024, 256, 0, stream>>>(x, xb);
    cvt_w<<<1281, 256, 0, stream>>>(W_qg, W_kv, W_proj, pow_p, Wt1, Wt2, powers);
    gemm1_mfma<<<dim3(BN_ / 128, 8), 256, 0, stream>>>(xb, Wt1, powers, q_pow, k_pow, g16, v16);
    kvmat_kernel<<<512, 256, 0, stream>>>(k_pow, v16, kv_part);
    kv_reduce<<<64, 256, 0, stream>>>(kv_part, kv_mat);
    conv_kernel<<<2048, 256, 0, stream>>>(v16, dwc_w, dwc_b, vl16);
    att_a2<<<2048, 256, 0, stream>>>(q_pow, kv_mat, vl16, g16, A2);
    gemm2_mfma<<<dim3(BN_ / 128, 2), 256, 0, stream>>>(A2, Wt2, b_proj, out);
}

// Round 4
// 256.687 us; speedup vs baseline: 3.4494x; 1.4852x over previous
//
#include <hip/hip_runtime.h>
#include <hip/hip_bf16.h>
#include <math.h>

#define B_ 8
#define N_ 4096
#define C_ 256
#define H_ 8
#define HD_ 32
#define BN_ (B_ * N_)  // 32768
#define E_ ((size_t)BN_ * C_)  // 8388608

typedef __attribute__((ext_vector_type(8))) short short8;
typedef __attribute__((ext_vector_type(4))) float f32x4;

__device__ __forceinline__ float b2f(__hip_bfloat16 x) { return __bfloat162float(x); }

// async global->LDS, 16 bytes per lane; lds base must be wave-uniform
__device__ __forceinline__ void gl_lds16(const void* gp, void* lp) {
    __builtin_amdgcn_global_load_lds(
        (const __attribute__((address_space(1))) unsigned int*)gp,
        (__attribute__((address_space(3))) unsigned int*)lp,
        16, 0, 0);
}

// fast |v|^p via hardware log2/exp2
__device__ __forceinline__ float fast_abspow(float v, float p) {
    float av = fabsf(v);
    return (av > 0.f) ? exp2f(p * __log2f(av)) : 0.f;
}

// ---- convert x (fp32 -> bf16), vectorized ----
__global__ __launch_bounds__(256) void cvt_x(const float* __restrict__ x,
                                             __hip_bfloat16* __restrict__ xb) {
    size_t i = ((size_t)blockIdx.x * 256 + threadIdx.x) * 4;
    float4 v = *(const float4*)&x[i];
    xb[i + 0] = __float2bfloat16(v.x);
    xb[i + 1] = __float2bfloat16(v.y);
    xb[i + 2] = __float2bfloat16(v.z);
    xb[i + 3] = __float2bfloat16(v.w);
}

// ---- transpose-convert weights to [N][K] bf16 via LDS tiles; also powers ----
// blocks 0..31: Wqg (256x512), 32..63: Wkv, 64..79: Wp (256x256), 80: powers
__global__ __launch_bounds__(256) void cvt_w(
    const float* __restrict__ Wqg, const float* __restrict__ Wkv,
    const float* __restrict__ Wp, const float* __restrict__ pp,
    __hip_bfloat16* __restrict__ Wt1, __hip_bfloat16* __restrict__ Wt2,
    float* __restrict__ powers) {
    int bid = blockIdx.x, t = threadIdx.x;
    if (bid == 80) {
        powers[t] = 1.0f + 4.0f / (1.0f + expf(-pp[t]));
        return;
    }
    __shared__ float tile[64][65];
    const float* src;
    __hip_bfloat16* dst;
    int scols, tr, tc, dn0;
    if (bid < 32)      { src = Wqg; scols = 512; tr = bid >> 3;        tc = bid & 7;        dst = Wt1; dn0 = tc * 64; }
    else if (bid < 64) { src = Wkv; scols = 512; tr = (bid - 32) >> 3; tc = (bid - 32) & 7; dst = Wt1; dn0 = 512 + tc * 64; }
    else               { src = Wp;  scols = 256; tr = (bid - 64) >> 2; tc = (bid - 64) & 3; dst = Wt2; dn0 = tc * 64; }
    int tx = t & 63, ty = t >> 6;
    #pragma unroll
    for (int i = 0; i < 16; i++) {
        int r = ty + i * 4;
        tile[r][tx] = src[(size_t)(tr * 64 + r) * scols + tc * 64 + tx];
    }
    __syncthreads();
    #pragma unroll
    for (int i = 0; i < 16; i++) {
        int n_local = ty + i * 4;
        dst[(size_t)(dn0 + n_local) * 256 + tr * 64 + tx] = __float2bfloat16(tile[tx][n_local]);
    }
}

// ---- GEMM1: (32768x256 bf16) @ (256x1024 via Wt1[n][k]) -> epilogue split ----
// grid (256, 8); block tile 128x128, BK=32
__global__ __launch_bounds__(256) void gemm1_mfma(
    const __hip_bfloat16* __restrict__ xb, const __hip_bfloat16* __restrict__ Wt1,
    const float* __restrict__ powers,
    __hip_bfloat16* __restrict__ q16, __hip_bfloat16* __restrict__ k16,
    __hip_bfloat16* __restrict__ g16, __hip_bfloat16* __restrict__ v16)
{
    __shared__ __align__(16) short As[128 * 32];
    __shared__ __align__(16) short Bs[128 * 32];
    int t = threadIdx.x;
    int w = t >> 6, l = t & 63;
    int row0 = blockIdx.x * 128;
    int col0 = blockIdx.y * 128;
    int wm = (w >> 1) * 64, wn = (w & 1) * 64;
    int lane15 = l & 15, quad = l >> 4;
    int rr = (l >> 2), kk = (l & 3) * 8;

    f32x4 acc[4][4];
    #pragma unroll
    for (int mi = 0; mi < 4; mi++)
        #pragma unroll
        for (int ni = 0; ni < 4; ni++) acc[mi][ni] = (f32x4){0.f, 0.f, 0.f, 0.f};

    for (int k0 = 0; k0 < 256; k0 += 32) {
        #pragma unroll
        for (int i = 0; i < 2; i++) {
            int r = (w * 2 + i) * 16 + rr;
            gl_lds16(&xb[(size_t)(row0 + r) * 256 + k0 + kk], &As[(w * 2 + i) * 512]);
            gl_lds16(&Wt1[(size_t)(col0 + r) * 256 + k0 + kk], &Bs[(w * 2 + i) * 512]);
        }
        __syncthreads();
        short8 a[4], b[4];
        #pragma unroll
        for (int mi = 0; mi < 4; mi++)
            a[mi] = *(const short8*)&As[(wm + mi * 16 + lane15) * 32 + quad * 8];
        #pragma unroll
        for (int ni = 0; ni < 4; ni++)
            b[ni] = *(const short8*)&Bs[(wn + ni * 16 + lane15) * 32 + quad * 8];
        #pragma unroll
        for (int mi = 0; mi < 4; mi++)
            #pragma unroll
            for (int ni = 0; ni < 4; ni++)
                acc[mi][ni] = __builtin_amdgcn_mfma_f32_16x16x32_bf16(a[mi], b[ni], acc[mi][ni], 0, 0, 0);
        __syncthreads();
    }

    int region = blockIdx.y >> 1;  // 0:q 1:g 2:k 3:v
    #pragma unroll
    for (int mi = 0; mi < 4; mi++) {
        #pragma unroll
        for (int ni = 0; ni < 4; ni++) {
            int row = row0 + wm + mi * 16 + quad * 4;
            int col = col0 + wn + ni * 16 + lane15;
            int c255 = col & 255;
            float p = powers[c255];
            #pragma unroll
            for (int r = 0; r < 4; r++) {
                float v = acc[mi][ni][r];
                size_t idx = (size_t)(row + r) * 256 + c255;
                if (region == 0) {
                    q16[idx] = __float2bfloat16(fast_abspow(v, p));
                } else if (region == 1) {
                    g16[idx] = __float2bfloat16(v);
                } else if (region == 2) {
                    k16[idx] = __float2bfloat16(fast_abspow(v, p));
                } else {
                    v16[idx] = __float2bfloat16(v);
                }
            }
        }
    }
}

// ---- kvmat partials: grid 512 = bh*8+seg, each covers 512 n ----
__global__ __launch_bounds__(256) void kvmat_kernel(
    const __hip_bfloat16* __restrict__ k16, const __hip_bfloat16* __restrict__ v16,
    float* __restrict__ kv_part)
{
    __shared__ float Kl[16][32];
    __shared__ float Vl[16][32];
    int t = threadIdx.x;
    int bid = blockIdx.x;
    int bh = bid >> 3, seg = bid & 7;
    int b = bh >> 3, h = bh & 7;
    int d = t & 31, e0 = (t >> 5) * 4;
    float acc[4] = {0.f, 0.f, 0.f, 0.f};
    const size_t base = (size_t)b * N_ * 256 + h * 32;
    for (int n0 = seg * 512; n0 < (seg + 1) * 512; n0 += 16) {
        #pragma unroll
        for (int i = 0; i < 4; i++) {
            int idx = t + i * 256;
            int nn = (idx >> 5) & 15, dd = idx & 31;
            if (idx < 512) Kl[nn][dd] = b2f(k16[base + (size_t)(n0 + nn) * 256 + dd]);
            else           Vl[nn][dd] = b2f(v16[base + (size_t)(n0 + nn) * 256 + dd]);
        }
        __syncthreads();
        #pragma unroll
        for (int nn = 0; nn < 16; nn++) {
            float kd = Kl[nn][d];
            #pragma unroll
            for (int j = 0; j < 4; j++) acc[j] += kd * Vl[nn][e0 + j];
        }
        __syncthreads();
    }
    #pragma unroll
    for (int j = 0; j < 4; j++) kv_part[(size_t)bid * 1024 + d * 32 + e0 + j] = acc[j];
}

__global__ __launch_bounds__(256) void kv_reduce(
    const float* __restrict__ kv_part, float* __restrict__ kv_mat)
{
    int bh = blockIdx.x, t = threadIdx.x;
    #pragma unroll
    for (int j = 0; j < 4; j++) {
        int i = t + j * 256;
        float s = 0.f;
        #pragma unroll
        for (int seg = 0; seg < 8; seg++) s += kv_part[((size_t)bh * 8 + seg) * 1024 + i];
        kv_mat[(size_t)bh * 1024 + i] = s;
    }
}

// ---- depthwise 5x5 conv on bf16 images ----
__global__ __launch_bounds__(256) void conv_kernel(
    const __hip_bfloat16* __restrict__ v16,
    const float* __restrict__ w, const float* __restrict__ bias,
    __hip_bfloat16* __restrict__ vloc)
{
    __shared__ float img[4096];
    __shared__ float wl[25];
    int t = threadIdx.x;
    int gid = blockIdx.x;  // G*32 + DD
    int DD = gid & 31;
    for (int i = 0; i < 16; i++) img[t + i * 256] = b2f(v16[(size_t)gid * 4096 + t + i * 256]);
    if (t < 25) wl[t] = w[DD * 25 + t];
    __syncthreads();
    float bs = bias[DD];
    for (int i = 0; i < 16; i++) {
        int p = t + i * 256;
        int y = p >> 6, xx = p & 63;
        float acc = 0.f;
        #pragma unroll
        for (int ky = 0; ky < 5; ky++) {
            int yy = y + ky - 2;
            if (yy < 0 || yy >= 64) continue;
            #pragma unroll
            for (int kx = 0; kx < 5; kx++) {
                int xc = xx + kx - 2;
                if (xc < 0 || xc >= 64) continue;
                acc += wl[ky * 5 + kx] * img[yy * 64 + xc];
            }
        }
        vloc[(size_t)gid * 4096 + p] = __float2bfloat16(acc + bs);
    }
}

// ---- att + vloc-shuffle + gate -> A2 bf16; 64 rows per block (512 blocks) ----
__global__ __launch_bounds__(256) void att_a2(
    const __hip_bfloat16* __restrict__ q16, const float* __restrict__ kv_mat,
    const __hip_bfloat16* __restrict__ vloc, const __hip_bfloat16* __restrict__ g16,
    __hip_bfloat16* __restrict__ A2)
{
    __shared__ float kvm[8192];
    __shared__ float ql[16][256];
    int t = threadIdx.x;
    int R0 = blockIdx.x * 64;
    int b = R0 >> 12, n0 = R0 & 4095;
    for (int i = 0; i < 32; i++) kvm[t + i * 256] = kv_mat[(size_t)b * 8192 + t + i * 256];
    int c = t, h = t >> 5, e = t & 31;
    const float* kvh = &kvm[h * 1024];
    size_t img = (size_t)((b * 8 + (c & 7)) * 32 + (c >> 3)) * 4096 + n0;
    for (int chunk = 0; chunk < 4; chunk++) {
        __syncthreads();
        int Rb = R0 + chunk * 16;
        #pragma unroll
        for (int i = 0; i < 16; i++) ql[i][t] = b2f(q16[(size_t)(Rb + i) * 256 + t]);
        __syncthreads();
        #pragma unroll
        for (int i = 0; i < 16; i++) {
            float acc = 0.f;
            #pragma unroll
            for (int d = 0; d < 32; d++) acc += ql[i][h * 32 + d] * kvh[d * 32 + e];
            int r = chunk * 16 + i;
            float vl = b2f(vloc[img + r]);
            float gg = b2f(g16[(size_t)(Rb + i) * 256 + c]);
            A2[(size_t)(Rb + i) * 256 + c] = __float2bfloat16((acc + vl) * gg);
        }
    }
}

// ---- GEMM2: (32768x256 bf16 A2) @ (Wt2[n][k]) + b_proj -> fp32 out ----
__global__ __launch_bounds__(256) void gemm2_mfma(
    const __hip_bfloat16* __restrict__ A2, const __hip_bfloat16* __restrict__ Wt2,
    const float* __restrict__ bp, float* __restrict__ out)
{
    __shared__ __align__(16) short As[128 * 32];
    __shared__ __align__(16) short Bs[128 * 32];
    int t = threadIdx.x;
    int w = t >> 6, l = t & 63;
    int row0 = blockIdx.x * 128;
    int col0 = blockIdx.y * 128;
    int wm = (w >> 1) * 64, wn = (w & 1) * 64;
    int lane15 = l & 15, quad = l >> 4;
    int rr = (l >> 2), kk = (l & 3) * 8;

    f32x4 acc[4][4];
    #pragma unroll
    for (int mi = 0; mi < 4; mi++)
        #pragma unroll
        for (int ni = 0; ni < 4; ni++) acc[mi][ni] = (f32x4){0.f, 0.f, 0.f, 0.f};

    for (int k0 = 0; k0 < 256; k0 += 32) {
        #pragma unroll
        for (int i = 0; i < 2; i++) {
            int r = (w * 2 + i) * 16 + rr;
            gl_lds16(&A2[(size_t)(row0 + r) * 256 + k0 + kk], &As[(w * 2 + i) * 512]);
            gl_lds16(&Wt2[(size_t)(col0 + r) * 256 + k0 + kk], &Bs[(w * 2 + i) * 512]);
        }
        __syncthreads();
        short8 a[4], b[4];
        #pragma unroll
        for (int mi = 0; mi < 4; mi++)
            a[mi] = *(const short8*)&As[(wm + mi * 16 + lane15) * 32 + quad * 8];
        #pragma unroll
        for (int ni = 0; ni < 4; ni++)
            b[ni] = *(const short8*)&Bs[(wn + ni * 16 + lane15) * 32 + quad * 8];
        #pragma unroll
        for (int mi = 0; mi < 4; mi++)
            #pragma unroll
            for (int ni = 0; ni < 4; ni++)
                acc[mi][ni] = __builtin_amdgcn_mfma_f32_16x16x32_bf16(a[mi], b[ni], acc[mi][ni], 0, 0, 0);
        __syncthreads();
    }

    #pragma unroll
    for (int mi = 0; mi < 4; mi++) {
        #pragma unroll
        for (int ni = 0; ni < 4; ni++) {
            int row = row0 + wm + mi * 16 + quad * 4;
            int col = col0 + wn + ni * 16 + lane15;
            float bv = bp[col];
            #pragma unroll
            for (int r = 0; r < 4; r++)
                out[(size_t)(row + r) * 256 + col] = acc[mi][ni][r] + bv;
        }
    }
}

extern "C" void kernel_launch(void* const* d_in, const int* in_sizes, int n_in,
                              void* d_out, int out_size, void* d_ws, size_t ws_size,
                              hipStream_t stream) {
    const float* x      = (const float*)d_in[0];
    const float* W_qg   = (const float*)d_in[1];
    const float* W_kv   = (const float*)d_in[2];
    const float* W_proj = (const float*)d_in[3];
    const float* b_proj = (const float*)d_in[4];
    const float* dwc_w  = (const float*)d_in[5];
    const float* dwc_b  = (const float*)d_in[6];
    const float* pow_p  = (const float*)d_in[7];
    float* out = (float*)d_out;

    float* ws = (float*)d_ws;
    const size_t E = E_;
    __hip_bfloat16* q16  = (__hip_bfloat16*)ws;                  // E bf16
    __hip_bfloat16* k16  = (__hip_bfloat16*)(ws + E / 2);        // E bf16
    __hip_bfloat16* vl16 = k16;                                  // alias: k dead after kvmat
    __hip_bfloat16* g16  = (__hip_bfloat16*)(ws + E);            // E bf16
    __hip_bfloat16* v16  = (__hip_bfloat16*)(ws + 3 * E / 2);    // E bf16
    __hip_bfloat16* xb   = (__hip_bfloat16*)(ws + 2 * E);        // E bf16, reused as A2
    __hip_bfloat16* A2   = xb;
    float* kv_part = ws + 5 * E / 2;                 // 524288 floats
    float* kv_mat  = kv_part + 524288;               // 65536 floats
    __hip_bfloat16* Wt1 = (__hip_bfloat16*)(kv_mat + 65536);     // 262144 bf16
    __hip_bfloat16* Wt2 = Wt1 + 262144;              // 65536 bf16
    float* powers = (float*)(Wt2 + 65536);           // 256 floats

    cvt_x<<<E / 1024, 256, 0, stream>>>(x, xb);
    cvt_w<<<81, 256, 0, stream>>>(W_qg, W_kv, W_proj, pow_p, Wt1, Wt2, powers);
    gemm1_mfma<<<dim3(BN_ / 128, 8), 256, 0, stream>>>(xb, Wt1, powers, q16, k16, g16, v16);
    kvmat_kernel<<<512, 256, 0, stream>>>(k16, v16, kv_part);
    kv_reduce<<<64, 256, 0, stream>>>(kv_part, kv_mat);
    conv_kernel<<<2048, 256, 0, stream>>>(v16, dwc_w, dwc_b, vl16);
    att_a2<<<512, 256, 0, stream>>>(q16, kv_mat, vl16, g16, A2);
    gemm2_mfma<<<dim3(BN_ / 128, 2), 256, 0, stream>>>(A2, Wt2, b_proj, out);
}

// Round 5
// 240.685 us; speedup vs baseline: 3.6787x; 1.0665x over previous
//
#include <hip/hip_runtime.h>
#include <hip/hip_bf16.h>
#include <math.h>

#define B_ 8
#define N_ 4096
#define C_ 256
#define H_ 8
#define HD_ 32
#define BN_ (B_ * N_)  // 32768
#define E_ ((size_t)BN_ * C_)  // 8388608

typedef __attribute__((ext_vector_type(8))) short short8;
typedef __attribute__((ext_vector_type(4))) float f32x4;

__device__ __forceinline__ float b2f(__hip_bfloat16 x) { return __bfloat162float(x); }

// async global->LDS, 16 bytes per lane; lds dst must be wave-uniform base + lane*16
__device__ __forceinline__ void gl_lds16(const void* gp, void* lp) {
    __builtin_amdgcn_global_load_lds(
        (const __attribute__((address_space(1))) unsigned int*)gp,
        (__attribute__((address_space(3))) unsigned int*)lp,
        16, 0, 0);
}

__device__ __forceinline__ float fast_abspow(float v, float p) {
    float av = fabsf(v);
    return (av > 0.f) ? exp2f(p * __log2f(av)) : 0.f;
}

__device__ __forceinline__ float bf_lo(unsigned u) { return __uint_as_float(u << 16); }
__device__ __forceinline__ float bf_hi(unsigned u) { return __uint_as_float(u & 0xffff0000u); }

// ---- convert x (fp32 -> bf16) ----
__global__ __launch_bounds__(256) void cvt_x(const float* __restrict__ x,
                                             __hip_bfloat16* __restrict__ xb) {
    size_t i = ((size_t)blockIdx.x * 256 + threadIdx.x) * 4;
    float4 v = *(const float4*)&x[i];
    xb[i + 0] = __float2bfloat16(v.x);
    xb[i + 1] = __float2bfloat16(v.y);
    xb[i + 2] = __float2bfloat16(v.z);
    xb[i + 3] = __float2bfloat16(v.w);
}

// ---- transpose-convert weights to [N][K] bf16 via LDS tiles; also powers ----
__global__ __launch_bounds__(256) void cvt_w(
    const float* __restrict__ Wqg, const float* __restrict__ Wkv,
    const float* __restrict__ Wp, const float* __restrict__ pp,
    __hip_bfloat16* __restrict__ Wt1, __hip_bfloat16* __restrict__ Wt2,
    float* __restrict__ powers) {
    int bid = blockIdx.x, t = threadIdx.x;
    if (bid == 80) {
        powers[t] = 1.0f + 4.0f / (1.0f + expf(-pp[t]));
        return;
    }
    __shared__ float tile[64][65];
    const float* src;
    __hip_bfloat16* dst;
    int scols, tr, tc, dn0;
    if (bid < 32)      { src = Wqg; scols = 512; tr = bid >> 3;        tc = bid & 7;        dst = Wt1; dn0 = tc * 64; }
    else if (bid < 64) { src = Wkv; scols = 512; tr = (bid - 32) >> 3; tc = (bid - 32) & 7; dst = Wt1; dn0 = 512 + tc * 64; }
    else               { src = Wp;  scols = 256; tr = (bid - 64) >> 2; tc = (bid - 64) & 3; dst = Wt2; dn0 = tc * 64; }
    int tx = t & 63, ty = t >> 6;
    #pragma unroll
    for (int i = 0; i < 16; i++) {
        int r = ty + i * 4;
        tile[r][tx] = src[(size_t)(tr * 64 + r) * scols + tc * 64 + tx];
    }
    __syncthreads();
    #pragma unroll
    for (int i = 0; i < 16; i++) {
        int n_local = ty + i * 4;
        dst[(size_t)(dn0 + n_local) * 256 + tr * 64 + tx] = __float2bfloat16(tile[tx][n_local]);
    }
}

// ---- GEMM1: 128x128 tile, BK=64 (kh-split LDS: [kh][128][32]) ----
__global__ __launch_bounds__(256) void gemm1_mfma(
    const __hip_bfloat16* __restrict__ xb, const __hip_bfloat16* __restrict__ Wt1,
    const float* __restrict__ powers,
    __hip_bfloat16* __restrict__ q16, __hip_bfloat16* __restrict__ k16,
    __hip_bfloat16* __restrict__ g16, __hip_bfloat16* __restrict__ v16)
{
    __shared__ __align__(16) unsigned short As[2 * 128 * 32];
    __shared__ __align__(16) unsigned short Bs[2 * 128 * 32];
    int t = threadIdx.x;
    int w = t >> 6, l = t & 63;
    int row0 = blockIdx.x * 128;
    int col0 = blockIdx.y * 128;
    int wm = (w >> 1) * 64, wn = (w & 1) * 64;
    int lane15 = l & 15, quad = l >> 4;
    int srow = l >> 2;          // 0..15 within 16-row group
    int skcol = (l & 3) * 8;    // bf16 offset within 32-k

    f32x4 acc[4][4];
    #pragma unroll
    for (int mi = 0; mi < 4; mi++)
        #pragma unroll
        for (int ni = 0; ni < 4; ni++) acc[mi][ni] = (f32x4){0.f, 0.f, 0.f, 0.f};

    for (int k0 = 0; k0 < 256; k0 += 64) {
        #pragma unroll
        for (int kh = 0; kh < 2; kh++) {
            #pragma unroll
            for (int i = 0; i < 2; i++) {
                int r = i * 64 + w * 16 + srow;
                int kc = k0 + kh * 32 + skcol;
                gl_lds16(&xb[(size_t)(row0 + r) * 256 + kc],
                         &As[kh * 4096 + (i * 64 + w * 16) * 32]);
                gl_lds16(&Wt1[(size_t)(col0 + r) * 256 + kc],
                         &Bs[kh * 4096 + (i * 64 + w * 16) * 32]);
            }
        }
        __syncthreads();
        #pragma unroll
        for (int kh = 0; kh < 2; kh++) {
            short8 a[4], b[4];
            #pragma unroll
            for (int mi = 0; mi < 4; mi++)
                a[mi] = *(const short8*)&As[kh * 4096 + (wm + mi * 16 + lane15) * 32 + quad * 8];
            #pragma unroll
            for (int ni = 0; ni < 4; ni++)
                b[ni] = *(const short8*)&Bs[kh * 4096 + (wn + ni * 16 + lane15) * 32 + quad * 8];
            #pragma unroll
            for (int mi = 0; mi < 4; mi++)
                #pragma unroll
                for (int ni = 0; ni < 4; ni++)
                    acc[mi][ni] = __builtin_amdgcn_mfma_f32_16x16x32_bf16(a[mi], b[ni], acc[mi][ni], 0, 0, 0);
        }
        __syncthreads();
    }

    int region = blockIdx.y >> 1;  // 0:q 1:g 2:k 3:v
    #pragma unroll
    for (int mi = 0; mi < 4; mi++) {
        #pragma unroll
        for (int ni = 0; ni < 4; ni++) {
            int row = row0 + wm + mi * 16 + quad * 4;
            int col = col0 + wn + ni * 16 + lane15;
            int c255 = col & 255;
            float p = powers[c255];
            #pragma unroll
            for (int r = 0; r < 4; r++) {
                float v = acc[mi][ni][r];
                size_t idx = (size_t)(row + r) * 256 + c255;
                if (region == 0) {
                    q16[idx] = __float2bfloat16(fast_abspow(v, p));
                } else if (region == 1) {
                    g16[idx] = __float2bfloat16(v);
                } else if (region == 2) {
                    k16[idx] = __float2bfloat16(fast_abspow(v, p));
                } else {
                    v16[idx] = __float2bfloat16(v);
                }
            }
        }
    }
}

// ---- kvmat partials: grid 512 = b*64+seg (64 rows each), no LDS ----
// part[bseg][e*256 + h*32 + d] += k[n, h*32+d] * v[n, h*32+e]
__global__ __launch_bounds__(256) void kvmat_kernel(
    const __hip_bfloat16* __restrict__ k16, const __hip_bfloat16* __restrict__ v16,
    float* __restrict__ kv_part)
{
    int t = threadIdx.x;
    int bid = blockIdx.x;
    int b = bid >> 6, seg = bid & 63;
    int h = t >> 5;
    float acc[32];
    #pragma unroll
    for (int e = 0; e < 32; e++) acc[e] = 0.f;
    const size_t base = (size_t)b * N_ * 256;
    int n0 = seg * 64;
    for (int n = n0; n < n0 + 64; n++) {
        float kd = b2f(k16[base + (size_t)n * 256 + t]);
        const uint4* vp = (const uint4*)(v16 + base + (size_t)n * 256 + h * 32);
        uint4 va = vp[0], vb = vp[1], vc = vp[2], vd = vp[3];
        unsigned us[16] = {va.x, va.y, va.z, va.w, vb.x, vb.y, vb.z, vb.w,
                           vc.x, vc.y, vc.z, vc.w, vd.x, vd.y, vd.z, vd.w};
        #pragma unroll
        for (int j = 0; j < 16; j++) {
            acc[2 * j]     += kd * bf_lo(us[j]);
            acc[2 * j + 1] += kd * bf_hi(us[j]);
        }
    }
    float* dst = kv_part + (size_t)bid * 8192;
    #pragma unroll
    for (int e = 0; e < 32; e++) dst[e * 256 + t] = acc[e];
}

// ---- reduce 64 segs -> kv_mat2[b][e*256 + h*32 + d] ; grid 64 = b*8+chunk ----
__global__ __launch_bounds__(256) void kv_reduce(
    const float* __restrict__ kv_part, float* __restrict__ kv_mat2)
{
    int bid = blockIdx.x, t = threadIdx.x;
    int b = bid >> 3, chunk = bid & 7;
    #pragma unroll
    for (int j = 0; j < 4; j++) {
        int i = chunk * 1024 + j * 256 + t;
        float s = 0.f;
        for (int seg = 0; seg < 64; seg++)
            s += kv_part[((size_t)b * 64 + seg) * 8192 + i];
        kv_mat2[(size_t)b * 8192 + i] = s;
    }
}

// ---- depthwise 5x5 conv on bf16 images ----
__global__ __launch_bounds__(256) void conv_kernel(
    const __hip_bfloat16* __restrict__ v16,
    const float* __restrict__ w, const float* __restrict__ bias,
    __hip_bfloat16* __restrict__ vloc)
{
    __shared__ float img[4096];
    __shared__ float wl[25];
    int t = threadIdx.x;
    int gid = blockIdx.x;  // G*32 + DD
    int DD = gid & 31;
    for (int i = 0; i < 16; i++) img[t + i * 256] = b2f(v16[(size_t)gid * 4096 + t + i * 256]);
    if (t < 25) wl[t] = w[DD * 25 + t];
    __syncthreads();
    float bs = bias[DD];
    for (int i = 0; i < 16; i++) {
        int p = t + i * 256;
        int y = p >> 6, xx = p & 63;
        float acc = 0.f;
        #pragma unroll
        for (int ky = 0; ky < 5; ky++) {
            int yy = y + ky - 2;
            if (yy < 0 || yy >= 64) continue;
            #pragma unroll
            for (int kx = 0; kx < 5; kx++) {
                int xc = xx + kx - 2;
                if (xc < 0 || xc >= 64) continue;
                acc += wl[ky * 5 + kx] * img[yy * 64 + xc];
            }
        }
        vloc[(size_t)gid * 4096 + p] = __float2bfloat16(acc + bs);
    }
}

// ---- fused att + gate + GEMM2: grid 512, 64 rows per block ----
// Phase A: A2[r][c] = (q_pow[R]·kv[c] + vloc + gate) into LDS (bf16, padded)
// Phase B: out[64x256] = A2 @ Wt2^T + b_proj  (MFMA, DMA-staged B tiles)
#define A2P 264  // padded row stride (shorts)
__global__ __launch_bounds__(256) void att_gemm2(
    const __hip_bfloat16* __restrict__ q16, const float* __restrict__ kv_mat2,
    const __hip_bfloat16* __restrict__ vloc, const __hip_bfloat16* __restrict__ g16,
    const __hip_bfloat16* __restrict__ Wt2, const float* __restrict__ bp,
    float* __restrict__ out)
{
    __shared__ __align__(16) unsigned short A2s[64 * A2P];
    __shared__ __align__(16) unsigned short Bs[256 * 32];
    int t = threadIdx.x;
    int w = t >> 6, l = t & 63;
    int r0 = blockIdx.x * 64;
    int b = r0 >> 12, n0 = r0 & 4095;

    // ---- Phase A ----
    int c = t, h = c >> 5, e = c & 31;
    float kvr[32];
    {
        const float4* kp = (const float4*)(kv_mat2 + (size_t)b * 8192 + (size_t)e * 256 + h * 32);
        #pragma unroll
        for (int j = 0; j < 8; j++) {
            float4 kv4 = kp[j];
            kvr[4 * j] = kv4.x; kvr[4 * j + 1] = kv4.y;
            kvr[4 * j + 2] = kv4.z; kvr[4 * j + 3] = kv4.w;
        }
    }
    size_t img = (size_t)((b * 8 + (c & 7)) * 32 + (c >> 3)) * 4096 + n0;
    for (int r = 0; r < 64; r++) {
        int R = r0 + r;
        const uint4* qp = (const uint4*)(q16 + (size_t)R * 256 + h * 32);
        uint4 qa = qp[0], qb = qp[1], qc = qp[2], qd = qp[3];
        unsigned qs[16] = {qa.x, qa.y, qa.z, qa.w, qb.x, qb.y, qb.z, qb.w,
                           qc.x, qc.y, qc.z, qc.w, qd.x, qd.y, qd.z, qd.w};
        float acc = 0.f;
        #pragma unroll
        for (int j = 0; j < 16; j++)
            acc += bf_lo(qs[j]) * kvr[2 * j] + bf_hi(qs[j]) * kvr[2 * j + 1];
        float vl = b2f(vloc[img + r]);
        float gg = b2f(g16[(size_t)R * 256 + c]);
        __hip_bfloat16 o = __float2bfloat16((acc + vl) * gg);
        A2s[r * A2P + c] = *(unsigned short*)&o;
    }

    // ---- Phase B ----
    int wm = (w & 1) * 32, wn = (w >> 1) * 128;
    int lane15 = l & 15, quad = l >> 4;
    f32x4 acc2[2][8];
    #pragma unroll
    for (int mi = 0; mi < 2; mi++)
        #pragma unroll
        for (int ni = 0; ni < 8; ni++) acc2[mi][ni] = (f32x4){0.f, 0.f, 0.f, 0.f};

    for (int k0 = 0; k0 < 256; k0 += 32) {
        __syncthreads();  // protect Bs reuse (and A2s writes on first iter)
        #pragma unroll
        for (int i = 0; i < 4; i++) {
            int ncol = i * 64 + w * 16 + (l >> 2);
            gl_lds16(&Wt2[(size_t)ncol * 256 + k0 + (l & 3) * 8],
                     &Bs[(i * 64 + w * 16) * 32]);
        }
        __syncthreads();
        short8 a[2], bb[8];
        #pragma unroll
        for (int mi = 0; mi < 2; mi++)
            a[mi] = *(const short8*)&A2s[(wm + mi * 16 + lane15) * A2P + k0 + quad * 8];
        #pragma unroll
        for (int ni = 0; ni < 8; ni++)
            bb[ni] = *(const short8*)&Bs[(wn + ni * 16 + lane15) * 32 + quad * 8];
        #pragma unroll
        for (int mi = 0; mi < 2; mi++)
            #pragma unroll
            for (int ni = 0; ni < 8; ni++)
                acc2[mi][ni] = __builtin_amdgcn_mfma_f32_16x16x32_bf16(a[mi], bb[ni], acc2[mi][ni], 0, 0, 0);
    }

    #pragma unroll
    for (int mi = 0; mi < 2; mi++) {
        #pragma unroll
        for (int ni = 0; ni < 8; ni++) {
            int row = r0 + wm + mi * 16 + quad * 4;
            int col = wn + ni * 16 + lane15;
            float bv = bp[col];
            #pragma unroll
            for (int r = 0; r < 4; r++)
                out[(size_t)(row + r) * 256 + col] = acc2[mi][ni][r] + bv;
        }
    }
}

extern "C" void kernel_launch(void* const* d_in, const int* in_sizes, int n_in,
                              void* d_out, int out_size, void* d_ws, size_t ws_size,
                              hipStream_t stream) {
    const float* x      = (const float*)d_in[0];
    const float* W_qg   = (const float*)d_in[1];
    const float* W_kv   = (const float*)d_in[2];
    const float* W_proj = (const float*)d_in[3];
    const float* b_proj = (const float*)d_in[4];
    const float* dwc_w  = (const float*)d_in[5];
    const float* dwc_b  = (const float*)d_in[6];
    const float* pow_p  = (const float*)d_in[7];
    float* out = (float*)d_out;

    float* ws = (float*)d_ws;
    const size_t E = E_;
    __hip_bfloat16* q16  = (__hip_bfloat16*)ws;                  // E bf16
    __hip_bfloat16* k16  = (__hip_bfloat16*)(ws + E / 2);        // E bf16
    __hip_bfloat16* vl16 = k16;                                  // alias: k dead after kvmat
    __hip_bfloat16* g16  = (__hip_bfloat16*)(ws + E);            // E bf16
    __hip_bfloat16* v16  = (__hip_bfloat16*)(ws + 3 * E / 2);    // E bf16
    __hip_bfloat16* xb   = (__hip_bfloat16*)(ws + 2 * E);        // E bf16
    float* kv_part = ws + 5 * E / 2;                             // 512*8192 floats (16 MB)
    float* kv_mat2 = kv_part + 512 * 8192;                       // 65536 floats
    __hip_bfloat16* Wt1 = (__hip_bfloat16*)(kv_mat2 + 65536);    // 262144 bf16
    __hip_bfloat16* Wt2 = Wt1 + 262144;                          // 65536 bf16
    float* powers = (float*)(Wt2 + 65536);                       // 256 floats

    cvt_x<<<E / 1024, 256, 0, stream>>>(x, xb);
    cvt_w<<<81, 256, 0, stream>>>(W_qg, W_kv, W_proj, pow_p, Wt1, Wt2, powers);
    gemm1_mfma<<<dim3(BN_ / 128, 8), 256, 0, stream>>>(xb, Wt1, powers, q16, k16, g16, v16);
    kvmat_kernel<<<512, 256, 0, stream>>>(k16, v16, kv_part);
    kv_reduce<<<64, 256, 0, stream>>>(kv_part, kv_mat2);
    conv_kernel<<<2048, 256, 0, stream>>>(v16, dwc_w, dwc_b, vl16);
    att_gemm2<<<512, 256, 0, stream>>>(q16, kv_mat2, vl16, g16, Wt2, b_proj, out);
}

// Round 6
// 206.645 us; speedup vs baseline: 4.2847x; 1.1647x over previous
//
#include <hip/hip_runtime.h>
#include <hip/hip_bf16.h>
#include <math.h>

#define B_ 8
#define N_ 4096
#define C_ 256
#define H_ 8
#define HD_ 32
#define BN_ (B_ * N_)  // 32768
#define E_ ((size_t)BN_ * C_)  // 8388608

typedef __attribute__((ext_vector_type(8))) short short8;
typedef __attribute__((ext_vector_type(4))) float f32x4;

__device__ __forceinline__ float b2f(__hip_bfloat16 x) { return __bfloat162float(x); }

__device__ __forceinline__ void gl_lds16(const void* gp, void* lp) {
    __builtin_amdgcn_global_load_lds(
        (const __attribute__((address_space(1))) unsigned int*)gp,
        (__attribute__((address_space(3))) unsigned int*)lp,
        16, 0, 0);
}

__device__ __forceinline__ float fast_abspow(float v, float p) {
    float av = fabsf(v);
    return (av > 0.f) ? exp2f(p * __log2f(av)) : 0.f;
}

__device__ __forceinline__ float bf_lo(unsigned u) { return __uint_as_float(u << 16); }
__device__ __forceinline__ float bf_hi(unsigned u) { return __uint_as_float(u & 0xffff0000u); }
__device__ __forceinline__ unsigned short f2bfbits(float f) {
    __hip_bfloat16 h = __float2bfloat16(f);
    return *(unsigned short*)&h;
}

// ---- merged converts: blocks [0,8192): x -> bf16 ; [8192, 8272]: weights+powers ----
__global__ __launch_bounds__(256) void cvt_all(
    const float* __restrict__ x, const float* __restrict__ Wqg,
    const float* __restrict__ Wkv, const float* __restrict__ Wp,
    const float* __restrict__ pp,
    __hip_bfloat16* __restrict__ xb, __hip_bfloat16* __restrict__ Wt1,
    __hip_bfloat16* __restrict__ Wt2, float* __restrict__ powers)
{
    int t = threadIdx.x;
    int bid0 = blockIdx.x;
    if (bid0 < 8192) {
        size_t i = ((size_t)bid0 * 256 + t) * 4;
        float4 v = *(const float4*)&x[i];
        xb[i + 0] = __float2bfloat16(v.x);
        xb[i + 1] = __float2bfloat16(v.y);
        xb[i + 2] = __float2bfloat16(v.z);
        xb[i + 3] = __float2bfloat16(v.w);
        return;
    }
    int bid = bid0 - 8192;
    if (bid == 80) {
        powers[t] = 1.0f + 4.0f / (1.0f + expf(-pp[t]));
        return;
    }
    __shared__ float tile[64][65];
    const float* src;
    __hip_bfloat16* dst;
    int scols, tr, tc, dn0;
    if (bid < 32)      { src = Wqg; scols = 512; tr = bid >> 3;        tc = bid & 7;        dst = Wt1; dn0 = tc * 64; }
    else if (bid < 64) { src = Wkv; scols = 512; tr = (bid - 32) >> 3; tc = (bid - 32) & 7; dst = Wt1; dn0 = 512 + tc * 64; }
    else               { src = Wp;  scols = 256; tr = (bid - 64) >> 2; tc = (bid - 64) & 3; dst = Wt2; dn0 = tc * 64; }
    int tx = t & 63, ty = t >> 6;
    #pragma unroll
    for (int i = 0; i < 16; i++) {
        int r = ty + i * 4;
        tile[r][tx] = src[(size_t)(tr * 64 + r) * scols + tc * 64 + tx];
    }
    __syncthreads();
    #pragma unroll
    for (int i = 0; i < 16; i++) {
        int n_local = ty + i * 4;
        dst[(size_t)(dn0 + n_local) * 256 + tr * 64 + tx] = __float2bfloat16(tile[tx][n_local]);
    }
}

// ---- GEMM1: 128x128 tile, BK=64 ----
__global__ __launch_bounds__(256) void gemm1_mfma(
    const __hip_bfloat16* __restrict__ xb, const __hip_bfloat16* __restrict__ Wt1,
    const float* __restrict__ powers,
    __hip_bfloat16* __restrict__ q16, __hip_bfloat16* __restrict__ k16,
    __hip_bfloat16* __restrict__ g16, __hip_bfloat16* __restrict__ v16)
{
    __shared__ __align__(16) unsigned short As[2 * 128 * 32];
    __shared__ __align__(16) unsigned short Bs[2 * 128 * 32];
    int t = threadIdx.x;
    int w = t >> 6, l = t & 63;
    int row0 = blockIdx.x * 128;
    int col0 = blockIdx.y * 128;
    int wm = (w >> 1) * 64, wn = (w & 1) * 64;
    int lane15 = l & 15, quad = l >> 4;
    int srow = l >> 2;
    int skcol = (l & 3) * 8;

    f32x4 acc[4][4];
    #pragma unroll
    for (int mi = 0; mi < 4; mi++)
        #pragma unroll
        for (int ni = 0; ni < 4; ni++) acc[mi][ni] = (f32x4){0.f, 0.f, 0.f, 0.f};

    for (int k0 = 0; k0 < 256; k0 += 64) {
        #pragma unroll
        for (int kh = 0; kh < 2; kh++) {
            #pragma unroll
            for (int i = 0; i < 2; i++) {
                int r = i * 64 + w * 16 + srow;
                int kc = k0 + kh * 32 + skcol;
                gl_lds16(&xb[(size_t)(row0 + r) * 256 + kc],
                         &As[kh * 4096 + (i * 64 + w * 16) * 32]);
                gl_lds16(&Wt1[(size_t)(col0 + r) * 256 + kc],
                         &Bs[kh * 4096 + (i * 64 + w * 16) * 32]);
            }
        }
        __syncthreads();
        #pragma unroll
        for (int kh = 0; kh < 2; kh++) {
            short8 a[4], b[4];
            #pragma unroll
            for (int mi = 0; mi < 4; mi++)
                a[mi] = *(const short8*)&As[kh * 4096 + (wm + mi * 16 + lane15) * 32 + quad * 8];
            #pragma unroll
            for (int ni = 0; ni < 4; ni++)
                b[ni] = *(const short8*)&Bs[kh * 4096 + (wn + ni * 16 + lane15) * 32 + quad * 8];
            #pragma unroll
            for (int mi = 0; mi < 4; mi++)
                #pragma unroll
                for (int ni = 0; ni < 4; ni++)
                    acc[mi][ni] = __builtin_amdgcn_mfma_f32_16x16x32_bf16(a[mi], b[ni], acc[mi][ni], 0, 0, 0);
        }
        __syncthreads();
    }

    int region = blockIdx.y >> 1;
    #pragma unroll
    for (int mi = 0; mi < 4; mi++) {
        #pragma unroll
        for (int ni = 0; ni < 4; ni++) {
            int row = row0 + wm + mi * 16 + quad * 4;
            int col = col0 + wn + ni * 16 + lane15;
            int c255 = col & 255;
            float p = powers[c255];
            #pragma unroll
            for (int r = 0; r < 4; r++) {
                float v = acc[mi][ni][r];
                size_t idx = (size_t)(row + r) * 256 + c255;
                if (region == 0) {
                    q16[idx] = __float2bfloat16(fast_abspow(v, p));
                } else if (region == 1) {
                    g16[idx] = __float2bfloat16(v);
                } else if (region == 2) {
                    k16[idx] = __float2bfloat16(fast_abspow(v, p));
                } else {
                    v16[idx] = __float2bfloat16(v);
                }
            }
        }
    }
}

// ---- kvmat partials: grid 256 = b*32+seg (128 n each), LDS-staged panels ----
__global__ __launch_bounds__(256) void kvmat_kernel(
    const __hip_bfloat16* __restrict__ k16, const __hip_bfloat16* __restrict__ v16,
    float* __restrict__ kv_part)
{
    __shared__ __align__(16) unsigned short Kl[16 * 256];
    __shared__ __align__(16) unsigned short Vl[16 * 256];
    int t = threadIdx.x;
    int bid = blockIdx.x;
    int b = bid >> 5, seg = bid & 31;
    int h = t >> 5;
    float acc[32];
    #pragma unroll
    for (int e = 0; e < 32; e++) acc[e] = 0.f;
    const size_t base = (size_t)b * N_ * 256;
    int row = t >> 4, colb = (t & 15) * 16;
    for (int n0 = seg * 128; n0 < seg * 128 + 128; n0 += 16) {
        const uint4* ks = (const uint4*)(k16 + base + (size_t)(n0 + row) * 256 + colb);
        uint4 ka = ks[0], kb = ks[1];
        const uint4* vs = (const uint4*)(v16 + base + (size_t)(n0 + row) * 256 + colb);
        uint4 va = vs[0], vb = vs[1];
        __syncthreads();
        uint4* kd4 = (uint4*)&Kl[row * 256 + colb];
        kd4[0] = ka; kd4[1] = kb;
        uint4* vd4 = (uint4*)&Vl[row * 256 + colb];
        vd4[0] = va; vd4[1] = vb;
        __syncthreads();
        #pragma unroll
        for (int nn = 0; nn < 16; nn++) {
            unsigned short ku = Kl[nn * 256 + t];
            float kd = bf_lo((unsigned)ku);
            const uint4* vp = (const uint4*)&Vl[nn * 256 + h * 32];
            uint4 v0 = vp[0], v1 = vp[1], v2 = vp[2], v3 = vp[3];
            unsigned us[16] = {v0.x, v0.y, v0.z, v0.w, v1.x, v1.y, v1.z, v1.w,
                               v2.x, v2.y, v2.z, v2.w, v3.x, v3.y, v3.z, v3.w};
            #pragma unroll
            for (int j = 0; j < 16; j++) {
                acc[2 * j]     += kd * bf_lo(us[j]);
                acc[2 * j + 1] += kd * bf_hi(us[j]);
            }
        }
    }
    float* dst = kv_part + (size_t)bid * 8192;
    #pragma unroll
    for (int e = 0; e < 32; e++) dst[e * 256 + t] = acc[e];
}

// ---- reduce 32 segs -> kv_mat2[b][e*256 + h*32 + d] ; grid 64 = b*8+chunk ----
__global__ __launch_bounds__(256) void kv_reduce(
    const float* __restrict__ kv_part, float* __restrict__ kv_mat2)
{
    int bid = blockIdx.x, t = threadIdx.x;
    int b = bid >> 3, chunk = bid & 7;
    #pragma unroll
    for (int j = 0; j < 4; j++) {
        int i = chunk * 1024 + j * 256 + t;
        float s = 0.f;
        for (int seg = 0; seg < 32; seg++)
            s += kv_part[((size_t)b * 32 + seg) * 8192 + i];
        kv_mat2[(size_t)b * 8192 + i] = s;
    }
}

// ---- depthwise 5x5 conv, vectorized ----
__global__ __launch_bounds__(256) void conv_kernel(
    const __hip_bfloat16* __restrict__ v16,
    const float* __restrict__ w, const float* __restrict__ bias,
    __hip_bfloat16* __restrict__ vloc)
{
    __shared__ __align__(16) float img[64 * 72];  // cols: 4 pad | 64 data | 4 pad
    __shared__ float wl[25];
    int t = threadIdx.x;
    int gid = blockIdx.x;
    int DD = gid & 31;
    if (t < 128) {
        int row = t >> 1, side = (t & 1) * 68;
        *(float4*)&img[row * 72 + side] = (float4){0.f, 0.f, 0.f, 0.f};
    }
    if (t < 25) wl[t] = w[DD * 25 + t];
    {
        int row = t >> 2, colb = (t & 3) * 16;
        const uint4* src = (const uint4*)(v16 + (size_t)gid * 4096 + row * 64 + colb);
        uint4 u0 = src[0], u1 = src[1];
        float4* d = (float4*)&img[row * 72 + 4 + colb];
        d[0] = (float4){bf_lo(u0.x), bf_hi(u0.x), bf_lo(u0.y), bf_hi(u0.y)};
        d[1] = (float4){bf_lo(u0.z), bf_hi(u0.z), bf_lo(u0.w), bf_hi(u0.w)};
        d[2] = (float4){bf_lo(u1.x), bf_hi(u1.x), bf_lo(u1.y), bf_hi(u1.y)};
        d[3] = (float4){bf_lo(u1.z), bf_hi(u1.z), bf_lo(u1.w), bf_hi(u1.w)};
    }
    __syncthreads();
    float bs = bias[DD];
    int x0 = (t & 15) * 4, yb = t >> 4;
    #pragma unroll
    for (int s = 0; s < 4; s++) {
        int y = yb + s * 16;
        float a0 = bs, a1 = bs, a2 = bs, a3 = bs;
        #pragma unroll
        for (int ky = 0; ky < 5; ky++) {
            int row = y + ky - 2;
            if (row < 0 || row >= 64) continue;
            const float* rp = &img[row * 72 + x0];
            float4 w0 = *(const float4*)rp;
            float4 w1 = *(const float4*)(rp + 4);
            float4 w2 = *(const float4*)(rp + 8);
            float win[12] = {w0.x, w0.y, w0.z, w0.w, w1.x, w1.y, w1.z, w1.w,
                             w2.x, w2.y, w2.z, w2.w};
            #pragma unroll
            for (int kx = 0; kx < 5; kx++) {
                float wt = wl[ky * 5 + kx];
                a0 += wt * win[2 + kx];
                a1 += wt * win[3 + kx];
                a2 += wt * win[4 + kx];
                a3 += wt * win[5 + kx];
            }
        }
        unsigned lo = (unsigned)f2bfbits(a0) | ((unsigned)f2bfbits(a1) << 16);
        unsigned hi = (unsigned)f2bfbits(a2) | ((unsigned)f2bfbits(a3) << 16);
        *(uint2*)(vloc + (size_t)gid * 4096 + y * 64 + x0) = (uint2){lo, hi};
    }
}

// ---- fused MFMA att + gate + GEMM2: grid 512, 64 rows per block ----
#define A2P 264
__global__ __launch_bounds__(256) void att_gemm2(
    const __hip_bfloat16* __restrict__ q16, const float* __restrict__ kv_mat2,
    const __hip_bfloat16* __restrict__ vloc, const __hip_bfloat16* __restrict__ g16,
    const __hip_bfloat16* __restrict__ Wt2, const float* __restrict__ bp,
    float* __restrict__ out)
{
    __shared__ __align__(16) unsigned short QA[64 * A2P];  // q staging, then A2
    __shared__ __align__(16) unsigned short Bs[256 * 32];
    int t = threadIdx.x;
    int w = t >> 6, l = t & 63;
    int r0 = blockIdx.x * 64;
    int b = r0 >> 12, n0 = r0 & 4095;
    int lane15 = l & 15, quad = l >> 4;
    int h0 = w * 2;

    // stage q[64][256] -> QA (coalesced)
    {
        const uint4* qsrc = (const uint4*)(q16 + (size_t)(r0 + (t >> 2)) * 256 + (t & 3) * 64);
        uint4* qdst = (uint4*)&QA[(t >> 2) * A2P + (t & 3) * 64];
        #pragma unroll
        for (int j = 0; j < 8; j++) qdst[j] = qsrc[j];
    }
    __syncthreads();

    // a-frags: 4 m-tiles x 2 heads
    short8 afr[4][2];
    #pragma unroll
    for (int m = 0; m < 4; m++)
        #pragma unroll
        for (int hh = 0; hh < 2; hh++)
            afr[m][hh] = *(const short8*)&QA[(m * 16 + lane15) * A2P + (h0 + hh) * 32 + quad * 8];

    // b-frags from global kv_mat2 (fp32 -> bf16): kv[h][e][d], n=e, k=d
    short8 bfr[2][2];
    #pragma unroll
    for (int hh = 0; hh < 2; hh++) {
        #pragma unroll
        for (int nt = 0; nt < 2; nt++) {
            const float4* kp = (const float4*)(kv_mat2 + (size_t)b * 8192 +
                (size_t)(nt * 16 + lane15) * 256 + (h0 + hh) * 32 + quad * 8);
            float4 ka = kp[0], kb = kp[1];
            short8 bb;
            bb[0] = (short)f2bfbits(ka.x); bb[1] = (short)f2bfbits(ka.y);
            bb[2] = (short)f2bfbits(ka.z); bb[3] = (short)f2bfbits(ka.w);
            bb[4] = (short)f2bfbits(kb.x); bb[5] = (short)f2bfbits(kb.y);
            bb[6] = (short)f2bfbits(kb.z); bb[7] = (short)f2bfbits(kb.w);
            bfr[hh][nt] = bb;
        }
    }

    // att MFMA
    f32x4 ac[4][2][2];
    #pragma unroll
    for (int m = 0; m < 4; m++)
        #pragma unroll
        for (int hh = 0; hh < 2; hh++)
            #pragma unroll
            for (int nt = 0; nt < 2; nt++)
                ac[m][hh][nt] = __builtin_amdgcn_mfma_f32_16x16x32_bf16(
                    afr[m][hh], bfr[hh][nt], (f32x4){0.f, 0.f, 0.f, 0.f}, 0, 0, 0);

    // epilogue: (att + vloc)*g -> bf16 A2 (same LDS buffer; wave-private col stripe)
    #pragma unroll
    for (int m = 0; m < 4; m++) {
        #pragma unroll
        for (int hh = 0; hh < 2; hh++) {
            #pragma unroll
            for (int nt = 0; nt < 2; nt++) {
                int col = (h0 + hh) * 32 + nt * 16 + lane15;
                int rowb = m * 16 + quad * 4;
                size_t img = ((size_t)((b * 8 + (col & 7)) * 32 + (col >> 3))) * 4096 + n0 + rowb;
                uint2 vv = *(const uint2*)(vloc + img);
                float vl[4] = {bf_lo(vv.x), bf_hi(vv.x), bf_lo(vv.y), bf_hi(vv.y)};
                #pragma unroll
                for (int i = 0; i < 4; i++) {
                    float gg = b2f(g16[(size_t)(r0 + rowb + i) * 256 + col]);
                    float val = (ac[m][hh][nt][i] + vl[i]) * gg;
                    QA[(rowb + i) * A2P + col] = f2bfbits(val);
                }
            }
        }
    }

    // ---- Phase B: out[64x256] = A2 @ Wt2^T + bp ----
    int wm = (w & 1) * 32, wn = (w >> 1) * 128;
    f32x4 acc2[2][8];
    #pragma unroll
    for (int mi = 0; mi < 2; mi++)
        #pragma unroll
        for (int ni = 0; ni < 8; ni++) acc2[mi][ni] = (f32x4){0.f, 0.f, 0.f, 0.f};

    for (int k0 = 0; k0 < 256; k0 += 32) {
        __syncthreads();
        #pragma unroll
        for (int i = 0; i < 4; i++) {
            int ncol = i * 64 + w * 16 + (l >> 2);
            gl_lds16(&Wt2[(size_t)ncol * 256 + k0 + (l & 3) * 8],
                     &Bs[(i * 64 + w * 16) * 32]);
        }
        __syncthreads();
        short8 a[2], bb[8];
        #pragma unroll
        for (int mi = 0; mi < 2; mi++)
            a[mi] = *(const short8*)&QA[(wm + mi * 16 + lane15) * A2P + k0 + quad * 8];
        #pragma unroll
        for (int ni = 0; ni < 8; ni++)
            bb[ni] = *(const short8*)&Bs[(wn + ni * 16 + lane15) * 32 + quad * 8];
        #pragma unroll
        for (int mi = 0; mi < 2; mi++)
            #pragma unroll
            for (int ni = 0; ni < 8; ni++)
                acc2[mi][ni] = __builtin_amdgcn_mfma_f32_16x16x32_bf16(a[mi], bb[ni], acc2[mi][ni], 0, 0, 0);
    }

    #pragma unroll
    for (int mi = 0; mi < 2; mi++) {
        #pragma unroll
        for (int ni = 0; ni < 8; ni++) {
            int row = r0 + wm + mi * 16 + quad * 4;
            int col = wn + ni * 16 + lane15;
            float bv = bp[col];
            #pragma unroll
            for (int r = 0; r < 4; r++)
                out[(size_t)(row + r) * 256 + col] = acc2[mi][ni][r] + bv;
        }
    }
}

extern "C" void kernel_launch(void* const* d_in, const int* in_sizes, int n_in,
                              void* d_out, int out_size, void* d_ws, size_t ws_size,
                              hipStream_t stream) {
    const float* x      = (const float*)d_in[0];
    const float* W_qg   = (const float*)d_in[1];
    const float* W_kv   = (const float*)d_in[2];
    const float* W_proj = (const float*)d_in[3];
    const float* b_proj = (const float*)d_in[4];
    const float* dwc_w  = (const float*)d_in[5];
    const float* dwc_b  = (const float*)d_in[6];
    const float* pow_p  = (const float*)d_in[7];
    float* out = (float*)d_out;

    float* ws = (float*)d_ws;
    const size_t E = E_;
    __hip_bfloat16* q16  = (__hip_bfloat16*)ws;                  // E bf16
    __hip_bfloat16* k16  = (__hip_bfloat16*)(ws + E / 2);        // E bf16
    __hip_bfloat16* vl16 = k16;                                  // alias: k dead after kvmat
    __hip_bfloat16* g16  = (__hip_bfloat16*)(ws + E);            // E bf16
    __hip_bfloat16* v16  = (__hip_bfloat16*)(ws + 3 * E / 2);    // E bf16
    __hip_bfloat16* xb   = (__hip_bfloat16*)(ws + 2 * E);        // E bf16
    float* kv_part = ws + 5 * E / 2;                             // 256*8192 floats (8 MB)
    float* kv_mat2 = kv_part + 256 * 8192;                       // 65536 floats
    __hip_bfloat16* Wt1 = (__hip_bfloat16*)(kv_mat2 + 65536);    // 262144 bf16
    __hip_bfloat16* Wt2 = Wt1 + 262144;                          // 65536 bf16
    float* powers = (float*)(Wt2 + 65536);                       // 256 floats

    cvt_all<<<8192 + 81, 256, 0, stream>>>(x, W_qg, W_kv, W_proj, pow_p, xb, Wt1, Wt2, powers);
    gemm1_mfma<<<dim3(BN_ / 128, 8), 256, 0, stream>>>(xb, Wt1, powers, q16, k16, g16, v16);
    kvmat_kernel<<<256, 256, 0, stream>>>(k16, v16, kv_part);
    kv_reduce<<<64, 256, 0, stream>>>(kv_part, kv_mat2);
    conv_kernel<<<2048, 256, 0, stream>>>(v16, dwc_w, dwc_b, vl16);
    att_gemm2<<<512, 256, 0, stream>>>(q16, kv_mat2, vl16, g16, Wt2, b_proj, out);
}